// Round 2
// baseline (234.184 us; speedup 1.0000x reference)
//
#include <hip/hip_runtime.h>
#include <hip/hip_bf16.h>

#define EPSV  1e-5f
#define QSC   0.0625f     // C^-0.5

typedef __attribute__((ext_vector_type(8))) __bf16 bfrag;   // MFMA A/B operand
typedef __attribute__((ext_vector_type(4))) float  f32x4;
typedef __attribute__((ext_vector_type(8))) short  s16x8;
typedef __attribute__((ext_vector_type(4))) short  s16x4;

static __device__ __forceinline__ short f2b(float f) {
    __hip_bfloat16 h = __float2bfloat16(f);
    return __builtin_bit_cast(short, h);
}

// async global->LDS, 16B per lane; LDS dest = wave-uniform base + lane*16
#define GLDS16(SRC, DST) __builtin_amdgcn_global_load_lds( \
    (__attribute__((address_space(1))) void*)(SRC),        \
    (__attribute__((address_space(3))) void*)(DST), 16, 0, 0)

// ---------------------------------------------------------------------------
// K0: weights fp32 [k][n] -> bf16 transposed [n][k]  (4 matrices: q,k,v,o)
// ---------------------------------------------------------------------------
__global__ __launch_bounds__(256) void prep_w(const float* __restrict__ wq,
                                              const float* __restrict__ wk,
                                              const float* __restrict__ wv,
                                              const float* __restrict__ wo,
                                              short* __restrict__ wt) {
    const int z = blockIdx.x >> 8;
    const int n = blockIdx.x & 255;
    const int k = threadIdx.x;
    const float* w = (z == 0) ? wq : (z == 1) ? wk : (z == 2) ? wv : wo;
    wt[(z * 256 + n) * 256 + k] = f2b(w[k * 256 + n]);
}

// ---------------------------------------------------------------------------
// K1a: GroupNorm partial sums
// ---------------------------------------------------------------------------
__global__ __launch_bounds__(256) void gn_part(const float* __restrict__ x,
                                               float* __restrict__ part) {
    const int b = blockIdx.x >> 3, ch = blockIdx.x & 7;
    const int t = threadIdx.x;
    const int c4 = t & 63;
    const int rr = t >> 6;
    float s1 = 0.f, s2 = 0.f;
    for (int i = 0; i < 32; ++i) {
        const int pos = ch * 128 + rr + (i << 2);
        const f32x4 v = *reinterpret_cast<const f32x4*>(x + (((b << 10) + pos) << 8) + (c4 << 2));
        s1 += v[0] + v[1] + v[2] + v[3];
        s2 += v[0]*v[0] + v[1]*v[1] + v[2]*v[2] + v[3]*v[3];
    }
    __shared__ float ls1[256], ls2[256];
    ls1[t] = s1; ls2[t] = s2;
    __syncthreads();
    if (t < 32) {
        float a1 = 0.f, a2 = 0.f;
        for (int r2 = 0; r2 < 4; ++r2)
            for (int e = 0; e < 2; ++e) {
                const int idx = r2 * 64 + t * 2 + e;
                a1 += ls1[idx]; a2 += ls2[idx];
            }
        part[((b * 8 + ch) * 32 + t) * 2 + 0] = a1;
        part[((b * 8 + ch) * 32 + t) * 2 + 1] = a2;
    }
}

// ---------------------------------------------------------------------------
// K1b: finalize stats -> per-(b,c) affine:  ft = x*cA + cB
// ---------------------------------------------------------------------------
__global__ __launch_bounds__(256) void gn_final(const float* __restrict__ part,
                                                const float* __restrict__ gns,
                                                const float* __restrict__ gnb,
                                                float* __restrict__ cA,
                                                float* __restrict__ cB) {
    const int b = blockIdx.x, c = threadIdx.x, g = c >> 3;
    float s1 = 0.f, s2 = 0.f;
    for (int ch = 0; ch < 8; ++ch) {
        s1 += part[((b * 8 + ch) * 32 + g) * 2 + 0];
        s2 += part[((b * 8 + ch) * 32 + g) * 2 + 1];
    }
    const float mean = s1 * (1.f / 8192.f);
    const float var  = s2 * (1.f / 8192.f) - mean * mean;
    const float rstd = rsqrtf(var + EPSV);
    const float a = rstd * gns[c];
    cA[(b << 8) + c] = a;
    cB[(b << 8) + c] = gnb[c] - mean * a;
}

// ---------------------------------------------------------------------------
// K2: fused GN-normalize + QKV projection.  q pre-scaled by C^-0.5.
// v written TRANSPOSED: vt[b][c][pos]  (paid once; attn reads it 16x)
// ---------------------------------------------------------------------------
__global__ __launch_bounds__(256) void qkv_gemm(const float* __restrict__ x,
                                                const float* __restrict__ cA,
                                                const float* __restrict__ cB,
                                                const short* __restrict__ wt,
                                                const float* __restrict__ bq,
                                                const float* __restrict__ bk,
                                                const float* __restrict__ bv,
                                                short* __restrict__ qo,
                                                short* __restrict__ ko,
                                                short* __restrict__ vtg) {
    __shared__ short At[64][264];
    __shared__ short Bt[256][40];

    const int t  = threadIdx.x;
    const int m0 = blockIdx.x * 64;
    const int b  = m0 >> 10;
    const int lane = t & 63, w = t >> 6;
    const int lr = lane & 15, lh = lane >> 4;

    {
        const int r = t >> 2, q4 = t & 3;
        const float* xrow = x + (m0 + r) * 256;
        const float* ca = cA + (b << 8);
        const float* cb = cB + (b << 8);
        for (int i = 0; i < 16; ++i) {
            const int c0 = (q4 + 4 * i) * 4;
            const f32x4 v  = *reinterpret_cast<const f32x4*>(xrow + c0);
            const f32x4 aa = *reinterpret_cast<const f32x4*>(ca + c0);
            const f32x4 bb = *reinterpret_cast<const f32x4*>(cb + c0);
            s16x4 o;
            for (int j = 0; j < 4; ++j) o[j] = f2b(v[j] * aa[j] + bb[j]);
            *reinterpret_cast<s16x4*>(&At[r][c0]) = o;
        }
    }

    for (int z = 0; z < 3; ++z) {
        f32x4 acc[4][4];
        for (int mi = 0; mi < 4; ++mi)
            for (int ni = 0; ni < 4; ++ni) acc[mi][ni] = (f32x4){0.f, 0.f, 0.f, 0.f};
        const short* wz = wt + z * 65536;
        for (int kt = 0; kt < 8; ++kt) {
            __syncthreads();
            {
                const short* src = wz + t * 256 + kt * 32;
                for (int ii = 0; ii < 4; ++ii)
                    *reinterpret_cast<s16x8*>(&Bt[t][ii * 8]) =
                        *reinterpret_cast<const s16x8*>(src + ii * 8);
            }
            __syncthreads();
            bfrag af[4];
#pragma unroll
            for (int mi = 0; mi < 4; ++mi)
                af[mi] = *reinterpret_cast<const bfrag*>(&At[mi * 16 + lr][kt * 32 + lh * 8]);
#pragma unroll
            for (int ni = 0; ni < 4; ++ni) {
                const bfrag bf = *reinterpret_cast<const bfrag*>(&Bt[w * 64 + ni * 16 + lr][lh * 8]);
#pragma unroll
                for (int mi = 0; mi < 4; ++mi)
                    acc[mi][ni] = __builtin_amdgcn_mfma_f32_16x16x32_bf16(af[mi], bf, acc[mi][ni], 0, 0, 0);
            }
        }
        if (z == 2) {
            // V: write transposed vt[b][col][pos], 8B contiguous per lane
            for (int ni = 0; ni < 4; ++ni) {
                const int col = w * 64 + ni * 16 + lr;
                const float bb = bv[col];
                for (int mi = 0; mi < 4; ++mi) {
                    const int pos = (m0 & 1023) + mi * 16 + lh * 4;
                    s16x4 ov;
                    for (int j = 0; j < 4; ++j) ov[j] = f2b(acc[mi][ni][j] + bb);
                    *reinterpret_cast<s16x4*>(&vtg[(((b << 8) + col) << 10) + pos]) = ov;
                }
            }
        } else {
            short* outp = (z == 0) ? qo : ko;
            const float* bias = (z == 0) ? bq : bk;
            const float s = (z == 0) ? QSC : 1.0f;
            for (int ni = 0; ni < 4; ++ni) {
                const int col = w * 64 + ni * 16 + lr;
                const float bsc = bias[col] * s;
                for (int mi = 0; mi < 4; ++mi) {
                    const int row = m0 + mi * 16 + lh * 4;
                    for (int j = 0; j < 4; ++j)
                        outp[(row + j) * 256 + col] = f2b(acc[mi][ni][j] * s + bsc);
                }
            }
        }
    }
}

// ---------------------------------------------------------------------------
// K3: flash attention.  grid = 512 (XCD-swizzled), 256 thr = 4 waves.
// K-tile [64 key][256 c] and V-tile [256 c][64 key] staged via
// global_load_lds into LINEAR LDS with XOR-swizzled (granule ^ row&7)
// source addresses -> conflict-free staging AND fragment reads.
// P is per-wave LDS (no barrier needed).  2 barriers/iter + 1 for K reuse;
// K(t+1) load hidden under softmax+PV.
// ---------------------------------------------------------------------------
__global__ __launch_bounds__(256) void attn(const short* __restrict__ qq,
                                            const short* __restrict__ kk,
                                            const short* __restrict__ vt,
                                            short* __restrict__ ao) {
    __shared__ __align__(1024) short Kt[64 * 256];   // 32 KB
    __shared__ __align__(1024) short Vt[256 * 64];   // 32 KB
    __shared__ __align__(1024) short Pl[4 * 16 * 64];// 8 KB

    int bid = blockIdx.x;
    bid = ((bid & 7) << 6) | (bid >> 3);   // XCD swizzle: 4 batches per XCD -> K/V L2-resident
    const int b = bid >> 4, qt = bid & 15;
    const int t = threadIdx.x;
    const int w = t >> 6, lane = t & 63;
    const int lr = lane & 15, lh = lane >> 4;
    const int qr0 = qt * 64 + w * 16;
    const int sw = lr & 7;                 // read-side swizzle key

    // Q fragments in registers (q pre-scaled by 1/16)
    bfrag qf[8];
    {
        const short* qp = qq + (((b << 10) + qr0 + lr) << 8) + lh * 8;
#pragma unroll
        for (int ks = 0; ks < 8; ++ks)
            qf[ks] = *reinterpret_cast<const bfrag*>(qp + ks * 32);
    }

    const short* kbase = kk + (((long)b << 10) << 8);
    const short* vbase = vt + (((long)b << 8) << 10);
    short* plw = &Pl[w << 10];

    auto stageK = [&](int kt) {
#pragma unroll
        for (int t2 = 0; t2 < 8; ++t2) {
            const int r  = w * 16 + t2 * 2 + (lane >> 5);      // dest row (key)
            const int gs = (lane & 31) ^ (r & 7);              // swizzled src granule
            GLDS16(kbase + ((kt * 64 + r) << 8) + (gs << 3),
                   &Kt[(w * 16 + t2 * 2) << 8]);
        }
    };
    auto stageV = [&](int kt) {
#pragma unroll
        for (int t2 = 0; t2 < 8; ++t2) {
            const int r  = w * 64 + t2 * 8 + (lane >> 3);      // dest row (channel)
            const int gs = (lane & 7) ^ (r & 7);
            GLDS16(vbase + (r << 10) + kt * 64 + (gs << 3),
                   &Vt[(w * 64 + t2 * 8) << 6]);
        }
    };

    f32x4 o[16];
#pragma unroll
    for (int ci = 0; ci < 16; ++ci) o[ci] = (f32x4){0.f, 0.f, 0.f, 0.f};
    float m[4]    = {-3e38f, -3e38f, -3e38f, -3e38f};
    float lsum[4] = {0.f, 0.f, 0.f, 0.f};

    stageK(0); stageV(0);

    for (int kt = 0; kt < 16; ++kt) {
        __syncthreads();   // tiles ready (vmcnt drained by compiler)

        // ---- S = q . k^T
        f32x4 sacc[4];
#pragma unroll
        for (int ni = 0; ni < 4; ++ni) sacc[ni] = (f32x4){0.f, 0.f, 0.f, 0.f};
#pragma unroll
        for (int ks = 0; ks < 8; ++ks) {
            const int gb = ks * 4 + lh;
#pragma unroll
            for (int ni = 0; ni < 4; ++ni) {
                const int row = ni * 16 + lr;
                const bfrag bf = *reinterpret_cast<const bfrag*>(
                    &Kt[(row << 8) + ((gb ^ sw) << 3)]);
                sacc[ni] = __builtin_amdgcn_mfma_f32_16x16x32_bf16(qf[ks], bf, sacc[ni], 0, 0, 0);
            }
        }
        __syncthreads();           // all waves done reading K[t]
        if (kt < 15) stageK(kt + 1);   // hidden under softmax + PV

        // ---- online softmax with defer-rescale (exact: skip when max unchanged)
        float p[4][4];
#pragma unroll
        for (int j = 0; j < 4; ++j) {
            float rm = fmaxf(fmaxf(sacc[0][j], sacc[1][j]), fmaxf(sacc[2][j], sacc[3][j]));
            rm = fmaxf(rm, __shfl_xor(rm, 1));
            rm = fmaxf(rm, __shfl_xor(rm, 2));
            rm = fmaxf(rm, __shfl_xor(rm, 4));
            rm = fmaxf(rm, __shfl_xor(rm, 8));
            const bool grow = rm > m[j];
            const float mn = grow ? rm : m[j];
            float rs = 0.f;
#pragma unroll
            for (int ni = 0; ni < 4; ++ni) { p[ni][j] = __expf(sacc[ni][j] - mn); rs += p[ni][j]; }
            rs += __shfl_xor(rs, 1); rs += __shfl_xor(rs, 2);
            rs += __shfl_xor(rs, 4); rs += __shfl_xor(rs, 8);
            if (grow) {
                const float sc = __expf(m[j] - rm);
                m[j] = rm;
                lsum[j] = lsum[j] * sc + rs;
#pragma unroll
                for (int ci = 0; ci < 16; ++ci) o[ci][j] *= sc;
            } else {
                lsum[j] += rs;
            }
        }

        // ---- stage P (per-wave region, swizzled; no barrier needed)
#pragma unroll
        for (int ni = 0; ni < 4; ++ni) {
            const int cb = ni * 16 + lr;
            const int gc = cb >> 3;
#pragma unroll
            for (int j = 0; j < 4; ++j) {
                const int q = lh * 4 + j;
                plw[(q << 6) + (((gc ^ (q & 7)) << 3) | (cb & 7))] = f2b(p[ni][j]);
            }
        }
        const bfrag pa0 = *reinterpret_cast<const bfrag*>(
            &plw[(lr << 6) + ((lh ^ sw) << 3)]);
        const bfrag pa1 = *reinterpret_cast<const bfrag*>(
            &plw[(lr << 6) + (((lh + 4) ^ sw) << 3)]);

        // ---- O += P . V
#pragma unroll
        for (int ci = 0; ci < 16; ++ci) {
            const int row = ci * 16 + lr;
            const bfrag vb0 = *reinterpret_cast<const bfrag*>(
                &Vt[(row << 6) + ((lh ^ sw) << 3)]);
            const bfrag vb1 = *reinterpret_cast<const bfrag*>(
                &Vt[(row << 6) + (((lh + 4) ^ sw) << 3)]);
            o[ci] = __builtin_amdgcn_mfma_f32_16x16x32_bf16(pa0, vb0, o[ci], 0, 0, 0);
            o[ci] = __builtin_amdgcn_mfma_f32_16x16x32_bf16(pa1, vb1, o[ci], 0, 0, 0);
        }
        __syncthreads();           // all waves done reading V[t] (drains K-load too)
        if (kt < 15) stageV(kt + 1);
    }

    // normalize + store
    for (int j = 0; j < 4; ++j) {
        const float inv = 1.0f / lsum[j];
        const int row = (b << 10) + qr0 + lh * 4 + j;
        for (int ci = 0; ci < 16; ++ci)
            ao[(row << 8) + ci * 16 + lr] = f2b(o[ci][j] * inv);
    }
}

// ---------------------------------------------------------------------------
// K4: output projection + bias + residual
// ---------------------------------------------------------------------------
__global__ __launch_bounds__(256) void oproj(const short* __restrict__ ao,
                                             const short* __restrict__ wto,
                                             const float* __restrict__ bo,
                                             const float* __restrict__ x,
                                             float* __restrict__ out) {
    __shared__ short At[64][264];
    __shared__ short Bt[256][40];

    const int t  = threadIdx.x;
    const int m0 = blockIdx.x * 64;
    const int lane = t & 63, w = t >> 6;
    const int lr = lane & 15, lh = lane >> 4;

    {
        const int r = t >> 2, q4 = t & 3;
        const short* ap = ao + (m0 + r) * 256;
        for (int i = 0; i < 8; ++i) {
            const int c0 = (q4 + 4 * i) * 8;
            *reinterpret_cast<s16x8*>(&At[r][c0]) = *reinterpret_cast<const s16x8*>(ap + c0);
        }
    }

    f32x4 acc[4][4];
    for (int mi = 0; mi < 4; ++mi)
        for (int ni = 0; ni < 4; ++ni) acc[mi][ni] = (f32x4){0.f, 0.f, 0.f, 0.f};

    for (int kt = 0; kt < 8; ++kt) {
        __syncthreads();
        {
            const short* src = wto + t * 256 + kt * 32;
            for (int ii = 0; ii < 4; ++ii)
                *reinterpret_cast<s16x8*>(&Bt[t][ii * 8]) =
                    *reinterpret_cast<const s16x8*>(src + ii * 8);
        }
        __syncthreads();
        bfrag af[4];
#pragma unroll
        for (int mi = 0; mi < 4; ++mi)
            af[mi] = *reinterpret_cast<const bfrag*>(&At[mi * 16 + lr][kt * 32 + lh * 8]);
#pragma unroll
        for (int ni = 0; ni < 4; ++ni) {
            const bfrag bf = *reinterpret_cast<const bfrag*>(&Bt[w * 64 + ni * 16 + lr][lh * 8]);
#pragma unroll
            for (int mi = 0; mi < 4; ++mi)
                acc[mi][ni] = __builtin_amdgcn_mfma_f32_16x16x32_bf16(af[mi], bf, acc[mi][ni], 0, 0, 0);
        }
    }

    for (int ni = 0; ni < 4; ++ni) {
        const int col = w * 64 + ni * 16 + lr;
        const float bb = bo[col];
        for (int mi = 0; mi < 4; ++mi) {
            const int row = m0 + mi * 16 + lh * 4;
            for (int j = 0; j < 4; ++j) {
                const int idx = (row + j) * 256 + col;
                out[idx] = acc[mi][ni][j] + bb + x[idx];
            }
        }
    }
}

// ---------------------------------------------------------------------------
extern "C" void kernel_launch(void* const* d_in, const int* in_sizes, int n_in,
                              void* d_out, int out_size, void* d_ws, size_t ws_size,
                              hipStream_t stream) {
    const float* x   = (const float*)d_in[0];
    const float* gns = (const float*)d_in[1];
    const float* gnb = (const float*)d_in[2];
    const float* Wq  = (const float*)d_in[3];
    const float* bq  = (const float*)d_in[4];
    const float* Wk  = (const float*)d_in[5];
    const float* bk  = (const float*)d_in[6];
    const float* Wv  = (const float*)d_in[7];
    const float* bv  = (const float*)d_in[8];
    const float* Wo  = (const float*)d_in[9];
    const float* bo  = (const float*)d_in[10];
    float* out = (float*)d_out;

    char* ws = (char*)d_ws;
    short* wt   = (short*)(ws);
    float* part = (float*)(ws + 524288);
    float* cA   = (float*)(ws + 589824);
    float* cB   = (float*)(ws + 622592);
    const size_t MB16 = 16777216;
    short* qb  = (short*)(ws + (1 << 20));
    short* kb  = (short*)(ws + (1 << 20) + MB16);
    short* vtb = (short*)(ws + (1 << 20) + 2 * MB16);
    short* aob = (short*)(ws + (1 << 20) + 3 * MB16);

    hipLaunchKernelGGL(prep_w,   dim3(1024), dim3(256), 0, stream, Wq, Wk, Wv, Wo, wt);
    hipLaunchKernelGGL(gn_part,  dim3(256),  dim3(256), 0, stream, x, part);
    hipLaunchKernelGGL(gn_final, dim3(32),   dim3(256), 0, stream, part, gns, gnb, cA, cB);
    hipLaunchKernelGGL(qkv_gemm, dim3(512),  dim3(256), 0, stream, x, cA, cB, wt, bq, bk, bv, qb, kb, vtb);
    hipLaunchKernelGGL(attn,     dim3(512),  dim3(256), 0, stream, qb, kb, vtb, aob);
    hipLaunchKernelGGL(oproj,    dim3(512),  dim3(256), 0, stream, aob, wt + 3 * 65536, bo, x, out);
}

// Round 3
// 198.510 us; speedup vs baseline: 1.1797x; 1.1797x over previous
//
#include <hip/hip_runtime.h>
#include <hip/hip_bf16.h>

#define EPSV  1e-5f
#define QSC   0.0625f     // C^-0.5

typedef __attribute__((ext_vector_type(8))) __bf16 bfrag;   // MFMA A/B operand
typedef __attribute__((ext_vector_type(4))) float  f32x4;
typedef __attribute__((ext_vector_type(8))) short  s16x8;
typedef __attribute__((ext_vector_type(4))) short  s16x4;

static __device__ __forceinline__ short f2b(float f) {
    __hip_bfloat16 h = __float2bfloat16(f);
    return __builtin_bit_cast(short, h);
}

// async global->LDS, 16B per lane; LDS dest = wave-uniform base + lane*16
#define GLDS16(SRC, DST) __builtin_amdgcn_global_load_lds( \
    (__attribute__((address_space(1))) void*)(SRC),        \
    (__attribute__((address_space(3))) void*)(DST), 16, 0, 0)

// ---------------------------------------------------------------------------
// K0: weights fp32 [k][n] -> bf16 transposed [n][k]  (4 matrices: q,k,v,o)
// ---------------------------------------------------------------------------
__global__ __launch_bounds__(256) void prep_w(const float* __restrict__ wq,
                                              const float* __restrict__ wk,
                                              const float* __restrict__ wv,
                                              const float* __restrict__ wo,
                                              short* __restrict__ wt) {
    const int z = blockIdx.x >> 8;
    const int n = blockIdx.x & 255;
    const int k = threadIdx.x;
    const float* w = (z == 0) ? wq : (z == 1) ? wk : (z == 2) ? wv : wo;
    wt[(z * 256 + n) * 256 + k] = f2b(w[k * 256 + n]);
}

// ---------------------------------------------------------------------------
// K1a: GroupNorm partial sums
// ---------------------------------------------------------------------------
__global__ __launch_bounds__(256) void gn_part(const float* __restrict__ x,
                                               float* __restrict__ part) {
    const int b = blockIdx.x >> 3, ch = blockIdx.x & 7;
    const int t = threadIdx.x;
    const int c4 = t & 63;
    const int rr = t >> 6;
    float s1 = 0.f, s2 = 0.f;
    for (int i = 0; i < 32; ++i) {
        const int pos = ch * 128 + rr + (i << 2);
        const f32x4 v = *reinterpret_cast<const f32x4*>(x + (((b << 10) + pos) << 8) + (c4 << 2));
        s1 += v[0] + v[1] + v[2] + v[3];
        s2 += v[0]*v[0] + v[1]*v[1] + v[2]*v[2] + v[3]*v[3];
    }
    __shared__ float ls1[256], ls2[256];
    ls1[t] = s1; ls2[t] = s2;
    __syncthreads();
    if (t < 32) {
        float a1 = 0.f, a2 = 0.f;
        for (int r2 = 0; r2 < 4; ++r2)
            for (int e = 0; e < 2; ++e) {
                const int idx = r2 * 64 + t * 2 + e;
                a1 += ls1[idx]; a2 += ls2[idx];
            }
        part[((b * 8 + ch) * 32 + t) * 2 + 0] = a1;
        part[((b * 8 + ch) * 32 + t) * 2 + 1] = a2;
    }
}

// ---------------------------------------------------------------------------
// K1b: finalize stats -> per-(b,c) affine:  ft = x*cA + cB
// ---------------------------------------------------------------------------
__global__ __launch_bounds__(256) void gn_final(const float* __restrict__ part,
                                                const float* __restrict__ gns,
                                                const float* __restrict__ gnb,
                                                float* __restrict__ cA,
                                                float* __restrict__ cB) {
    const int b = blockIdx.x, c = threadIdx.x, g = c >> 3;
    float s1 = 0.f, s2 = 0.f;
    for (int ch = 0; ch < 8; ++ch) {
        s1 += part[((b * 8 + ch) * 32 + g) * 2 + 0];
        s2 += part[((b * 8 + ch) * 32 + g) * 2 + 1];
    }
    const float mean = s1 * (1.f / 8192.f);
    const float var  = s2 * (1.f / 8192.f) - mean * mean;
    const float rstd = rsqrtf(var + EPSV);
    const float a = rstd * gns[c];
    cA[(b << 8) + c] = a;
    cB[(b << 8) + c] = gnb[c] - mean * a;
}

// ---------------------------------------------------------------------------
// K2: fused GN-normalize + QKV projection.  q pre-scaled by C^-0.5.
// v written TRANSPOSED: vt[b][c][pos]
// ---------------------------------------------------------------------------
__global__ __launch_bounds__(256) void qkv_gemm(const float* __restrict__ x,
                                                const float* __restrict__ cA,
                                                const float* __restrict__ cB,
                                                const short* __restrict__ wt,
                                                const float* __restrict__ bq,
                                                const float* __restrict__ bk,
                                                const float* __restrict__ bv,
                                                short* __restrict__ qo,
                                                short* __restrict__ ko,
                                                short* __restrict__ vtg) {
    __shared__ short At[64][264];
    __shared__ short Bt[256][40];

    const int t  = threadIdx.x;
    const int m0 = blockIdx.x * 64;
    const int b  = m0 >> 10;
    const int lane = t & 63, w = t >> 6;
    const int lr = lane & 15, lh = lane >> 4;

    {
        const int r = t >> 2, q4 = t & 3;
        const float* xrow = x + (m0 + r) * 256;
        const float* ca = cA + (b << 8);
        const float* cb = cB + (b << 8);
        for (int i = 0; i < 16; ++i) {
            const int c0 = (q4 + 4 * i) * 4;
            const f32x4 v  = *reinterpret_cast<const f32x4*>(xrow + c0);
            const f32x4 aa = *reinterpret_cast<const f32x4*>(ca + c0);
            const f32x4 bb = *reinterpret_cast<const f32x4*>(cb + c0);
            s16x4 o;
            for (int j = 0; j < 4; ++j) o[j] = f2b(v[j] * aa[j] + bb[j]);
            *reinterpret_cast<s16x4*>(&At[r][c0]) = o;
        }
    }

    for (int z = 0; z < 3; ++z) {
        f32x4 acc[4][4];
        for (int mi = 0; mi < 4; ++mi)
            for (int ni = 0; ni < 4; ++ni) acc[mi][ni] = (f32x4){0.f, 0.f, 0.f, 0.f};
        const short* wz = wt + z * 65536;
        for (int kt = 0; kt < 8; ++kt) {
            __syncthreads();
            {
                const short* src = wz + t * 256 + kt * 32;
                for (int ii = 0; ii < 4; ++ii)
                    *reinterpret_cast<s16x8*>(&Bt[t][ii * 8]) =
                        *reinterpret_cast<const s16x8*>(src + ii * 8);
            }
            __syncthreads();
            bfrag af[4];
#pragma unroll
            for (int mi = 0; mi < 4; ++mi)
                af[mi] = *reinterpret_cast<const bfrag*>(&At[mi * 16 + lr][kt * 32 + lh * 8]);
#pragma unroll
            for (int ni = 0; ni < 4; ++ni) {
                const bfrag bf = *reinterpret_cast<const bfrag*>(&Bt[w * 64 + ni * 16 + lr][lh * 8]);
#pragma unroll
                for (int mi = 0; mi < 4; ++mi)
                    acc[mi][ni] = __builtin_amdgcn_mfma_f32_16x16x32_bf16(af[mi], bf, acc[mi][ni], 0, 0, 0);
            }
        }
        if (z == 2) {
            for (int ni = 0; ni < 4; ++ni) {
                const int col = w * 64 + ni * 16 + lr;
                const float bb = bv[col];
                for (int mi = 0; mi < 4; ++mi) {
                    const int pos = (m0 & 1023) + mi * 16 + lh * 4;
                    s16x4 ov;
                    for (int j = 0; j < 4; ++j) ov[j] = f2b(acc[mi][ni][j] + bb);
                    *reinterpret_cast<s16x4*>(&vtg[(((b << 8) + col) << 10) + pos]) = ov;
                }
            }
        } else {
            short* outp = (z == 0) ? qo : ko;
            const float* bias = (z == 0) ? bq : bk;
            const float s = (z == 0) ? QSC : 1.0f;
            for (int ni = 0; ni < 4; ++ni) {
                const int col = w * 64 + ni * 16 + lr;
                const float bsc = bias[col] * s;
                for (int mi = 0; mi < 4; ++mi) {
                    const int row = m0 + mi * 16 + lh * 4;
                    for (int j = 0; j < 4; ++j)
                        outp[(row + j) * 256 + col] = f2b(acc[mi][ni][j] * s + bsc);
                }
            }
        }
    }
}

// ---------------------------------------------------------------------------
// K3: flash attention, pipelined.  grid = 512 (XCD-swizzled), 256 thr = 4 waves.
// Double-buffered K/V tiles staged via global_load_lds; raw s_barrier +
// counted vmcnt(16) keeps next-tile loads in flight across barriers.
// Swapped QK^T: mfma(K,Q) -> lane holds S[16 keys][q=lr]; softmax needs only
// 2 shuffles for max + 2 for sum; P staged as b64 swizzled writes.
// ---------------------------------------------------------------------------
__global__ __launch_bounds__(256) void attn(const short* __restrict__ qq,
                                            const short* __restrict__ kk,
                                            const short* __restrict__ vt,
                                            short* __restrict__ ao) {
    __shared__ __align__(1024) short Kt[2][64 * 256];   // 2 x 32 KB
    __shared__ __align__(1024) short Vt[2][256 * 64];   // 2 x 32 KB
    __shared__ __align__(1024) short Pl[4][16 * 64];    // 8 KB (per-wave)

    int bid = blockIdx.x;
    bid = ((bid & 7) << 6) | (bid >> 3);   // XCD swizzle: 2 batches/XCD resident in L2
    const int b = bid >> 4, qt = bid & 15;
    const int t = threadIdx.x;
    const int w = t >> 6, lane = t & 63;
    const int lr = lane & 15, lh = lane >> 4;
    const int qr0 = qt * 64 + w * 16;
    const int sw = lr & 7;

    // Q fragments in registers (q pre-scaled by 1/16); B-operand layout:
    // lane (lr,lh) holds Q[q=lr][c = ks*32 + lh*8 ..]
    bfrag qf[8];
    {
        const short* qp = qq + (((b << 10) + qr0 + lr) << 8) + lh * 8;
#pragma unroll
        for (int ks = 0; ks < 8; ++ks)
            qf[ks] = *reinterpret_cast<const bfrag*>(qp + ks * 32);
    }

    const short* kbase = kk + ((long)b << 18);
    const short* vbase = vt + ((long)b << 18);
    short* plw = Pl[w];

    auto stageK = [&](int kt_, int buf) {
#pragma unroll
        for (int t2 = 0; t2 < 8; ++t2) {
            const int rbase = w * 16 + t2 * 2;
            const int r  = rbase + (lane >> 5);
            const int gs = (lane & 31) ^ (r & 7);          // inverse-swizzled source
            GLDS16(kbase + ((kt_ * 64 + r) << 8) + (gs << 3), &Kt[buf][rbase << 8]);
        }
    };
    auto stageV = [&](int kt_, int buf) {
#pragma unroll
        for (int t2 = 0; t2 < 8; ++t2) {
            const int rbase = w * 64 + t2 * 8;
            const int r  = rbase + (lane >> 3);
            const int gs = (lane & 7) ^ (r & 7);
            GLDS16(vbase + (r << 10) + kt_ * 64 + (gs << 3), &Vt[buf][rbase << 6]);
        }
    };

    f32x4 o[16];
#pragma unroll
    for (int ci = 0; ci < 16; ++ci) o[ci] = (f32x4){0.f, 0.f, 0.f, 0.f};
    float m = -3e38f, lsum = 0.f;

    stageK(0, 0); stageV(0, 0);   // 16 loads in flight

    for (int kt = 0; kt < 16; ++kt) {
        const int cur = kt & 1;
        // barrier A: all waves done reading buf cur^1 (iter kt-1)
        __asm__ volatile("s_barrier" ::: "memory");
        if (kt < 15) {
            stageK(kt + 1, cur ^ 1);
            stageV(kt + 1, cur ^ 1);
            __asm__ volatile("s_waitcnt vmcnt(16)" ::: "memory");  // tile-kt loads done
        } else {
            __asm__ volatile("s_waitcnt vmcnt(0)" ::: "memory");
        }
        // barrier B: every wave's share of tile kt is resident
        __asm__ volatile("s_barrier" ::: "memory");

        // ---- S^T = K . Q : sacc[ni] holds S[key = ni*16 + lh*4 + r][q = lr]
        f32x4 sacc[4];
#pragma unroll
        for (int ni = 0; ni < 4; ++ni) sacc[ni] = (f32x4){0.f, 0.f, 0.f, 0.f};
        __builtin_amdgcn_s_setprio(1);
#pragma unroll
        for (int ks = 0; ks < 8; ++ks) {
#pragma unroll
            for (int ni = 0; ni < 4; ++ni) {
                const int row = ni * 16 + lr;
                const bfrag kf = *reinterpret_cast<const bfrag*>(
                    &Kt[cur][(row << 8) + ((((ks << 2) + lh) ^ sw) << 3)]);
                sacc[ni] = __builtin_amdgcn_mfma_f32_16x16x32_bf16(kf, qf[ks], sacc[ni], 0, 0, 0);
            }
        }
        __builtin_amdgcn_s_setprio(0);

        // ---- online softmax, per-lane state for q-row lr
        float rm = fmaxf(fmaxf(sacc[0][0], sacc[0][1]), fmaxf(sacc[0][2], sacc[0][3]));
#pragma unroll
        for (int ni = 1; ni < 4; ++ni)
            rm = fmaxf(rm, fmaxf(fmaxf(sacc[ni][0], sacc[ni][1]),
                                 fmaxf(sacc[ni][2], sacc[ni][3])));
        rm = fmaxf(rm, __shfl_xor(rm, 16));
        rm = fmaxf(rm, __shfl_xor(rm, 32));
        const float mn = fmaxf(m, rm);
        const float sc = __expf(m - mn);   // ==1 when max didn't grow
        m = mn;
        float p[4][4];
        float rs = 0.f;
#pragma unroll
        for (int ni = 0; ni < 4; ++ni)
#pragma unroll
            for (int r2 = 0; r2 < 4; ++r2) {
                p[ni][r2] = __expf(sacc[ni][r2] - mn);
                rs += p[ni][r2];
            }
        rs += __shfl_xor(rs, 16);
        rs += __shfl_xor(rs, 32);
        lsum = lsum * sc + rs;

        // broadcast rescale factor to O layout (q-row = lh*4+j lives at lane lh*4+j)
        float scb[4];
#pragma unroll
        for (int j = 0; j < 4; ++j) scb[j] = __shfl(sc, lh * 4 + j);
#pragma unroll
        for (int ci = 0; ci < 16; ++ci)
#pragma unroll
            for (int j = 0; j < 4; ++j) o[ci][j] *= scb[j];

        // ---- stage P: row q=lr, keys ni*16 + lh*4 + (0..3) as one b64 write
#pragma unroll
        for (int ni = 0; ni < 4; ++ni) {
            s16x4 pw;
#pragma unroll
            for (int r2 = 0; r2 < 4; ++r2) pw[r2] = f2b(p[ni][r2]);
            const int gc = (ni << 1) + (lh >> 1);          // granule of key block
            const int ad = (lr << 6) + ((gc ^ sw) << 3) + ((lh & 1) << 2);
            *reinterpret_cast<s16x4*>(&plw[ad]) = pw;
        }
        const bfrag pa0 = *reinterpret_cast<const bfrag*>(
            &plw[(lr << 6) + ((lh ^ sw) << 3)]);
        const bfrag pa1 = *reinterpret_cast<const bfrag*>(
            &plw[(lr << 6) + (((4 + lh) ^ sw) << 3)]);

        // ---- O += P . V
        __builtin_amdgcn_s_setprio(1);
#pragma unroll
        for (int ci = 0; ci < 16; ++ci) {
            const int row = (ci << 4) + lr;
            const bfrag vb0 = *reinterpret_cast<const bfrag*>(
                &Vt[cur][(row << 6) + ((lh ^ sw) << 3)]);
            const bfrag vb1 = *reinterpret_cast<const bfrag*>(
                &Vt[cur][(row << 6) + (((4 + lh) ^ sw) << 3)]);
            o[ci] = __builtin_amdgcn_mfma_f32_16x16x32_bf16(pa0, vb0, o[ci], 0, 0, 0);
            o[ci] = __builtin_amdgcn_mfma_f32_16x16x32_bf16(pa1, vb1, o[ci], 0, 0, 0);
        }
        __builtin_amdgcn_s_setprio(0);
    }

    // normalize + store;  O lane layout: row q = lh*4+j, col d = ci*16+lr
    float invb[4];
#pragma unroll
    for (int j = 0; j < 4; ++j) invb[j] = 1.0f / __shfl(lsum, lh * 4 + j);
#pragma unroll
    for (int j = 0; j < 4; ++j) {
        const int row = (b << 10) + qr0 + lh * 4 + j;
        for (int ci = 0; ci < 16; ++ci)
            ao[(row << 8) + (ci << 4) + lr] = f2b(o[ci][j] * invb[j]);
    }
}

// ---------------------------------------------------------------------------
// K4: output projection + bias + residual
// ---------------------------------------------------------------------------
__global__ __launch_bounds__(256) void oproj(const short* __restrict__ ao,
                                             const short* __restrict__ wto,
                                             const float* __restrict__ bo,
                                             const float* __restrict__ x,
                                             float* __restrict__ out) {
    __shared__ short At[64][264];
    __shared__ short Bt[256][40];

    const int t  = threadIdx.x;
    const int m0 = blockIdx.x * 64;
    const int lane = t & 63, w = t >> 6;
    const int lr = lane & 15, lh = lane >> 4;

    {
        const int r = t >> 2, q4 = t & 3;
        const short* ap = ao + (m0 + r) * 256;
        for (int i = 0; i < 8; ++i) {
            const int c0 = (q4 + 4 * i) * 8;
            *reinterpret_cast<s16x8*>(&At[r][c0]) = *reinterpret_cast<const s16x8*>(ap + c0);
        }
    }

    f32x4 acc[4][4];
    for (int mi = 0; mi < 4; ++mi)
        for (int ni = 0; ni < 4; ++ni) acc[mi][ni] = (f32x4){0.f, 0.f, 0.f, 0.f};

    for (int kt = 0; kt < 8; ++kt) {
        __syncthreads();
        {
            const short* src = wto + t * 256 + kt * 32;
            for (int ii = 0; ii < 4; ++ii)
                *reinterpret_cast<s16x8*>(&Bt[t][ii * 8]) =
                    *reinterpret_cast<const s16x8*>(src + ii * 8);
        }
        __syncthreads();
        bfrag af[4];
#pragma unroll
        for (int mi = 0; mi < 4; ++mi)
            af[mi] = *reinterpret_cast<const bfrag*>(&At[mi * 16 + lr][kt * 32 + lh * 8]);
#pragma unroll
        for (int ni = 0; ni < 4; ++ni) {
            const bfrag bf = *reinterpret_cast<const bfrag*>(&Bt[w * 64 + ni * 16 + lr][lh * 8]);
#pragma unroll
            for (int mi = 0; mi < 4; ++mi)
                acc[mi][ni] = __builtin_amdgcn_mfma_f32_16x16x32_bf16(af[mi], bf, acc[mi][ni], 0, 0, 0);
        }
    }

    for (int ni = 0; ni < 4; ++ni) {
        const int col = w * 64 + ni * 16 + lr;
        const float bb = bo[col];
        for (int mi = 0; mi < 4; ++mi) {
            const int row = m0 + mi * 16 + lh * 4;
            for (int j = 0; j < 4; ++j) {
                const int idx = (row + j) * 256 + col;
                out[idx] = acc[mi][ni][j] + bb + x[idx];
            }
        }
    }
}

// ---------------------------------------------------------------------------
extern "C" void kernel_launch(void* const* d_in, const int* in_sizes, int n_in,
                              void* d_out, int out_size, void* d_ws, size_t ws_size,
                              hipStream_t stream) {
    const float* x   = (const float*)d_in[0];
    const float* gns = (const float*)d_in[1];
    const float* gnb = (const float*)d_in[2];
    const float* Wq  = (const float*)d_in[3];
    const float* bq  = (const float*)d_in[4];
    const float* Wk  = (const float*)d_in[5];
    const float* bk  = (const float*)d_in[6];
    const float* Wv  = (const float*)d_in[7];
    const float* bv  = (const float*)d_in[8];
    const float* Wo  = (const float*)d_in[9];
    const float* bo  = (const float*)d_in[10];
    float* out = (float*)d_out;

    char* ws = (char*)d_ws;
    short* wt   = (short*)(ws);
    float* part = (float*)(ws + 524288);
    float* cA   = (float*)(ws + 589824);
    float* cB   = (float*)(ws + 622592);
    const size_t MB16 = 16777216;
    short* qb  = (short*)(ws + (1 << 20));
    short* kb  = (short*)(ws + (1 << 20) + MB16);
    short* vtb = (short*)(ws + (1 << 20) + 2 * MB16);
    short* aob = (short*)(ws + (1 << 20) + 3 * MB16);

    hipLaunchKernelGGL(prep_w,   dim3(1024), dim3(256), 0, stream, Wq, Wk, Wv, Wo, wt);
    hipLaunchKernelGGL(gn_part,  dim3(256),  dim3(256), 0, stream, x, part);
    hipLaunchKernelGGL(gn_final, dim3(32),   dim3(256), 0, stream, part, gns, gnb, cA, cB);
    hipLaunchKernelGGL(qkv_gemm, dim3(512),  dim3(256), 0, stream, x, cA, cB, wt, bq, bk, bv, qb, kb, vtb);
    hipLaunchKernelGGL(attn,     dim3(512),  dim3(256), 0, stream, qb, kb, vtb, aob);
    hipLaunchKernelGGL(oproj,    dim3(512),  dim3(256), 0, stream, aob, wt + 3 * 65536, bo, x, out);
}

// Round 4
// 167.463 us; speedup vs baseline: 1.3984x; 1.1854x over previous
//
#include <hip/hip_runtime.h>
#include <hip/hip_bf16.h>

#define EPSV  1e-5f
#define QSC   0.0625f     // C^-0.5

typedef __attribute__((ext_vector_type(8))) __bf16 bfrag;   // MFMA A/B operand
typedef __attribute__((ext_vector_type(4))) float  f32x4;
typedef __attribute__((ext_vector_type(8))) short  s16x8;
typedef __attribute__((ext_vector_type(4))) short  s16x4;

static __device__ __forceinline__ short f2b(float f) {
    __hip_bfloat16 h = __float2bfloat16(f);
    return __builtin_bit_cast(short, h);
}

// async global->LDS, 16B per lane; LDS dest = wave-uniform base + lane*16
#define GLDS16(SRC, DST) __builtin_amdgcn_global_load_lds( \
    (__attribute__((address_space(1))) void*)(SRC),        \
    (__attribute__((address_space(3))) void*)(DST), 16, 0, 0)

// ---------------------------------------------------------------------------
// K0: weights fp32 [k][n] -> bf16 transposed [n][k]  (4 matrices: q,k,v,o)
// ---------------------------------------------------------------------------
__global__ __launch_bounds__(256) void prep_w(const float* __restrict__ wq,
                                              const float* __restrict__ wk,
                                              const float* __restrict__ wv,
                                              const float* __restrict__ wo,
                                              short* __restrict__ wt) {
    const int z = blockIdx.x >> 8;
    const int n = blockIdx.x & 255;
    const int k = threadIdx.x;
    const float* w = (z == 0) ? wq : (z == 1) ? wk : (z == 2) ? wv : wo;
    wt[(z * 256 + n) * 256 + k] = f2b(w[k * 256 + n]);
}

// ---------------------------------------------------------------------------
// K1a: GroupNorm partial sums
// ---------------------------------------------------------------------------
__global__ __launch_bounds__(256) void gn_part(const float* __restrict__ x,
                                               float* __restrict__ part) {
    const int b = blockIdx.x >> 3, ch = blockIdx.x & 7;
    const int t = threadIdx.x;
    const int c4 = t & 63;
    const int rr = t >> 6;
    float s1 = 0.f, s2 = 0.f;
    for (int i = 0; i < 32; ++i) {
        const int pos = ch * 128 + rr + (i << 2);
        const f32x4 v = *reinterpret_cast<const f32x4*>(x + (((b << 10) + pos) << 8) + (c4 << 2));
        s1 += v[0] + v[1] + v[2] + v[3];
        s2 += v[0]*v[0] + v[1]*v[1] + v[2]*v[2] + v[3]*v[3];
    }
    __shared__ float ls1[256], ls2[256];
    ls1[t] = s1; ls2[t] = s2;
    __syncthreads();
    if (t < 32) {
        float a1 = 0.f, a2 = 0.f;
        for (int r2 = 0; r2 < 4; ++r2)
            for (int e = 0; e < 2; ++e) {
                const int idx = r2 * 64 + t * 2 + e;
                a1 += ls1[idx]; a2 += ls2[idx];
            }
        part[((b * 8 + ch) * 32 + t) * 2 + 0] = a1;
        part[((b * 8 + ch) * 32 + t) * 2 + 1] = a2;
    }
}

// ---------------------------------------------------------------------------
// K1b: finalize stats -> per-(b,c) affine:  ft = x*cA + cB
// ---------------------------------------------------------------------------
__global__ __launch_bounds__(256) void gn_final(const float* __restrict__ part,
                                                const float* __restrict__ gns,
                                                const float* __restrict__ gnb,
                                                float* __restrict__ cA,
                                                float* __restrict__ cB) {
    const int b = blockIdx.x, c = threadIdx.x, g = c >> 3;
    float s1 = 0.f, s2 = 0.f;
    for (int ch = 0; ch < 8; ++ch) {
        s1 += part[((b * 8 + ch) * 32 + g) * 2 + 0];
        s2 += part[((b * 8 + ch) * 32 + g) * 2 + 1];
    }
    const float mean = s1 * (1.f / 8192.f);
    const float var  = s2 * (1.f / 8192.f) - mean * mean;
    const float rstd = rsqrtf(var + EPSV);
    const float a = rstd * gns[c];
    cA[(b << 8) + c] = a;
    cB[(b << 8) + c] = gnb[c] - mean * a;
}

// ---------------------------------------------------------------------------
// K2: fused GN-normalize + QKV projection.  q pre-scaled by C^-0.5.
// v written TRANSPOSED: vt[b][c][pos]
// ---------------------------------------------------------------------------
__global__ __launch_bounds__(256) void qkv_gemm(const float* __restrict__ x,
                                                const float* __restrict__ cA,
                                                const float* __restrict__ cB,
                                                const short* __restrict__ wt,
                                                const float* __restrict__ bq,
                                                const float* __restrict__ bk,
                                                const float* __restrict__ bv,
                                                short* __restrict__ qo,
                                                short* __restrict__ ko,
                                                short* __restrict__ vtg) {
    __shared__ short At[64][264];
    __shared__ short Bt[256][40];

    const int t  = threadIdx.x;
    const int m0 = blockIdx.x * 64;
    const int b  = m0 >> 10;
    const int lane = t & 63, w = t >> 6;
    const int lr = lane & 15, lh = lane >> 4;

    {
        const int r = t >> 2, q4 = t & 3;
        const float* xrow = x + (m0 + r) * 256;
        const float* ca = cA + (b << 8);
        const float* cb = cB + (b << 8);
        for (int i = 0; i < 16; ++i) {
            const int c0 = (q4 + 4 * i) * 4;
            const f32x4 v  = *reinterpret_cast<const f32x4*>(xrow + c0);
            const f32x4 aa = *reinterpret_cast<const f32x4*>(ca + c0);
            const f32x4 bb = *reinterpret_cast<const f32x4*>(cb + c0);
            s16x4 o;
            for (int j = 0; j < 4; ++j) o[j] = f2b(v[j] * aa[j] + bb[j]);
            *reinterpret_cast<s16x4*>(&At[r][c0]) = o;
        }
    }

    for (int z = 0; z < 3; ++z) {
        f32x4 acc[4][4];
        for (int mi = 0; mi < 4; ++mi)
            for (int ni = 0; ni < 4; ++ni) acc[mi][ni] = (f32x4){0.f, 0.f, 0.f, 0.f};
        const short* wz = wt + z * 65536;
        for (int kt = 0; kt < 8; ++kt) {
            __syncthreads();
            {
                const short* src = wz + t * 256 + kt * 32;
                for (int ii = 0; ii < 4; ++ii)
                    *reinterpret_cast<s16x8*>(&Bt[t][ii * 8]) =
                        *reinterpret_cast<const s16x8*>(src + ii * 8);
            }
            __syncthreads();
            bfrag af[4];
#pragma unroll
            for (int mi = 0; mi < 4; ++mi)
                af[mi] = *reinterpret_cast<const bfrag*>(&At[mi * 16 + lr][kt * 32 + lh * 8]);
#pragma unroll
            for (int ni = 0; ni < 4; ++ni) {
                const bfrag bf = *reinterpret_cast<const bfrag*>(&Bt[w * 64 + ni * 16 + lr][lh * 8]);
#pragma unroll
                for (int mi = 0; mi < 4; ++mi)
                    acc[mi][ni] = __builtin_amdgcn_mfma_f32_16x16x32_bf16(af[mi], bf, acc[mi][ni], 0, 0, 0);
            }
        }
        if (z == 2) {
            for (int ni = 0; ni < 4; ++ni) {
                const int col = w * 64 + ni * 16 + lr;
                const float bb = bv[col];
                for (int mi = 0; mi < 4; ++mi) {
                    const int pos = (m0 & 1023) + mi * 16 + lh * 4;
                    s16x4 ov;
                    for (int j = 0; j < 4; ++j) ov[j] = f2b(acc[mi][ni][j] + bb);
                    *reinterpret_cast<s16x4*>(&vtg[(((b << 8) + col) << 10) + pos]) = ov;
                }
            }
        } else {
            short* outp = (z == 0) ? qo : ko;
            const float* bias = (z == 0) ? bq : bk;
            const float s = (z == 0) ? QSC : 1.0f;
            for (int ni = 0; ni < 4; ++ni) {
                const int col = w * 64 + ni * 16 + lr;
                const float bsc = bias[col] * s;
                for (int mi = 0; mi < 4; ++mi) {
                    const int row = m0 + mi * 16 + lh * 4;
                    for (int j = 0; j < 4; ++j)
                        outp[(row + j) * 256 + col] = f2b(acc[mi][ni][j] * s + bsc);
                }
            }
        }
    }
}

// ---------------------------------------------------------------------------
// K3: flash attention, 8 waves (512 thr), QBLK=128 per block.
// grid = 256 (XCD-swizzled) = 1 block/CU, 2 waves/SIMD.
// Double-buffered K/V via global_load_lds, raw s_barrier + counted vmcnt(8).
// Swapped QK^T (mfma(K,Q)); per-lane softmax (2 shuffles); wave-uniform
// skip-rescale; P staged as swizzled b64.
// ---------------------------------------------------------------------------
__global__ __launch_bounds__(512) void attn(const short* __restrict__ qq,
                                            const short* __restrict__ kk,
                                            const short* __restrict__ vt,
                                            short* __restrict__ ao) {
    __shared__ __align__(1024) short Kt[2][64 * 256];   // 2 x 32 KB
    __shared__ __align__(1024) short Vt[2][256 * 64];   // 2 x 32 KB
    __shared__ __align__(1024) short Pl[8][16 * 64];    // 16 KB (per-wave)

    int bid = blockIdx.x;
    bid = ((bid & 7) << 5) | (bid >> 3);   // XCD swizzle: 4 batches/XCD in L2
    const int b = bid >> 3, qt = bid & 7;
    const int t = threadIdx.x;
    const int w = t >> 6, lane = t & 63;
    const int lr = lane & 15, lh = lane >> 4;
    const int qr0 = qt * 128 + w * 16;
    const int sw = lr & 7;

    // Q fragments in registers (q pre-scaled by 1/16); B-operand layout:
    // lane (lr,lh) holds Q[q=lr][c = ks*32 + lh*8 ..]
    bfrag qf[8];
    {
        const short* qp = qq + (((b << 10) + qr0 + lr) << 8) + lh * 8;
#pragma unroll
        for (int ks = 0; ks < 8; ++ks)
            qf[ks] = *reinterpret_cast<const bfrag*>(qp + ks * 32);
    }

    const short* kbase = kk + ((long)b << 18);
    const short* vbase = vt + ((long)b << 18);
    short* plw = Pl[w];

    // per-wave staging share: K rows w*8..w*8+7 (4 x 2 rows),
    //                         V rows w*32..w*32+31 (4 x 8 rows)
    auto stageK = [&](int kt_, int buf) {
#pragma unroll
        for (int t2 = 0; t2 < 4; ++t2) {
            const int rbase = w * 8 + t2 * 2;
            const int r  = rbase + (lane >> 5);
            const int gs = (lane & 31) ^ (r & 7);          // inverse-swizzled source
            GLDS16(kbase + ((kt_ * 64 + r) << 8) + (gs << 3), &Kt[buf][rbase << 8]);
        }
    };
    auto stageV = [&](int kt_, int buf) {
#pragma unroll
        for (int t2 = 0; t2 < 4; ++t2) {
            const int rbase = w * 32 + t2 * 8;
            const int r  = rbase + (lane >> 3);
            const int gs = (lane & 7) ^ (r & 7);
            GLDS16(vbase + (r << 10) + kt_ * 64 + (gs << 3), &Vt[buf][rbase << 6]);
        }
    };

    f32x4 o[16];
#pragma unroll
    for (int ci = 0; ci < 16; ++ci) o[ci] = (f32x4){0.f, 0.f, 0.f, 0.f};
    float m = -3e38f, lsum = 0.f;

    stageK(0, 0); stageV(0, 0);   // 8 loads in flight per wave

    for (int kt = 0; kt < 16; ++kt) {
        const int cur = kt & 1;
        // barrier A: all waves done reading buf cur^1 (iter kt-1)
        __asm__ volatile("s_barrier" ::: "memory");
        if (kt < 15) {
            stageK(kt + 1, cur ^ 1);
            stageV(kt + 1, cur ^ 1);
            __asm__ volatile("s_waitcnt vmcnt(8)" ::: "memory");  // tile-kt loads done
        } else {
            __asm__ volatile("s_waitcnt vmcnt(0)" ::: "memory");
        }
        // barrier B: every wave's share of tile kt is resident
        __asm__ volatile("s_barrier" ::: "memory");

        // ---- S^T = K . Q : sacc[ni] holds S[key = ni*16 + lh*4 + r][q = lr]
        f32x4 sacc[4];
#pragma unroll
        for (int ni = 0; ni < 4; ++ni) sacc[ni] = (f32x4){0.f, 0.f, 0.f, 0.f};
        __builtin_amdgcn_s_setprio(1);
#pragma unroll
        for (int ks = 0; ks < 8; ++ks) {
#pragma unroll
            for (int ni = 0; ni < 4; ++ni) {
                const int row = ni * 16 + lr;
                const bfrag kf = *reinterpret_cast<const bfrag*>(
                    &Kt[cur][(row << 8) + ((((ks << 2) + lh) ^ sw) << 3)]);
                sacc[ni] = __builtin_amdgcn_mfma_f32_16x16x32_bf16(kf, qf[ks], sacc[ni], 0, 0, 0);
            }
        }
        __builtin_amdgcn_s_setprio(0);

        // ---- online softmax, per-lane state for q-row lr
        float rm = fmaxf(fmaxf(sacc[0][0], sacc[0][1]), fmaxf(sacc[0][2], sacc[0][3]));
#pragma unroll
        for (int ni = 1; ni < 4; ++ni)
            rm = fmaxf(rm, fmaxf(fmaxf(sacc[ni][0], sacc[ni][1]),
                                 fmaxf(sacc[ni][2], sacc[ni][3])));
        rm = fmaxf(rm, __shfl_xor(rm, 16));
        rm = fmaxf(rm, __shfl_xor(rm, 32));

        const bool grow = __any(rm > m);   // wave-uniform branch
        float p[4][4];
        float rs = 0.f;
        if (grow) {
            const float mn = fmaxf(m, rm);
            const float sc = __expf(m - mn);
            m = mn;
#pragma unroll
            for (int ni = 0; ni < 4; ++ni)
#pragma unroll
                for (int r2 = 0; r2 < 4; ++r2) {
                    p[ni][r2] = __expf(sacc[ni][r2] - mn);
                    rs += p[ni][r2];
                }
            rs += __shfl_xor(rs, 16);
            rs += __shfl_xor(rs, 32);
            lsum = lsum * sc + rs;
            // broadcast rescale to O layout (q-row lh*4+j lives at lane lh*4+j)
            float scb[4];
#pragma unroll
            for (int j = 0; j < 4; ++j) scb[j] = __shfl(sc, lh * 4 + j);
#pragma unroll
            for (int ci = 0; ci < 16; ++ci)
#pragma unroll
                for (int j = 0; j < 4; ++j) o[ci][j] *= scb[j];
        } else {
#pragma unroll
            for (int ni = 0; ni < 4; ++ni)
#pragma unroll
                for (int r2 = 0; r2 < 4; ++r2) {
                    p[ni][r2] = __expf(sacc[ni][r2] - m);
                    rs += p[ni][r2];
                }
            rs += __shfl_xor(rs, 16);
            rs += __shfl_xor(rs, 32);
            lsum += rs;
        }

        // ---- stage P: row q=lr, keys ni*16 + lh*4 + (0..3) as one b64 write
#pragma unroll
        for (int ni = 0; ni < 4; ++ni) {
            s16x4 pw;
#pragma unroll
            for (int r2 = 0; r2 < 4; ++r2) pw[r2] = f2b(p[ni][r2]);
            const int gc = (ni << 1) + (lh >> 1);          // granule of key block
            const int ad = (lr << 6) + ((gc ^ sw) << 3) + ((lh & 1) << 2);
            *reinterpret_cast<s16x4*>(&plw[ad]) = pw;
        }
        const bfrag pa0 = *reinterpret_cast<const bfrag*>(
            &plw[(lr << 6) + ((lh ^ sw) << 3)]);
        const bfrag pa1 = *reinterpret_cast<const bfrag*>(
            &plw[(lr << 6) + (((4 + lh) ^ sw) << 3)]);

        // ---- O += P . V
        __builtin_amdgcn_s_setprio(1);
#pragma unroll
        for (int ci = 0; ci < 16; ++ci) {
            const int row = (ci << 4) + lr;
            const bfrag vb0 = *reinterpret_cast<const bfrag*>(
                &Vt[cur][(row << 6) + ((lh ^ sw) << 3)]);
            const bfrag vb1 = *reinterpret_cast<const bfrag*>(
                &Vt[cur][(row << 6) + (((4 + lh) ^ sw) << 3)]);
            o[ci] = __builtin_amdgcn_mfma_f32_16x16x32_bf16(pa0, vb0, o[ci], 0, 0, 0);
            o[ci] = __builtin_amdgcn_mfma_f32_16x16x32_bf16(pa1, vb1, o[ci], 0, 0, 0);
        }
        __builtin_amdgcn_s_setprio(0);
    }

    // normalize + store;  O lane layout: row q = lh*4+j, col d = ci*16+lr
    float invb[4];
#pragma unroll
    for (int j = 0; j < 4; ++j) invb[j] = 1.0f / __shfl(lsum, lh * 4 + j);
#pragma unroll
    for (int j = 0; j < 4; ++j) {
        const int row = (b << 10) + qr0 + lh * 4 + j;
        for (int ci = 0; ci < 16; ++ci)
            ao[(row << 8) + (ci << 4) + lr] = f2b(o[ci][j] * invb[j]);
    }
}

// ---------------------------------------------------------------------------
// K4: output projection + bias + residual
// ---------------------------------------------------------------------------
__global__ __launch_bounds__(256) void oproj(const short* __restrict__ ao,
                                             const short* __restrict__ wto,
                                             const float* __restrict__ bo,
                                             const float* __restrict__ x,
                                             float* __restrict__ out) {
    __shared__ short At[64][264];
    __shared__ short Bt[256][40];

    const int t  = threadIdx.x;
    const int m0 = blockIdx.x * 64;
    const int lane = t & 63, w = t >> 6;
    const int lr = lane & 15, lh = lane >> 4;

    {
        const int r = t >> 2, q4 = t & 3;
        const short* ap = ao + (m0 + r) * 256;
        for (int i = 0; i < 8; ++i) {
            const int c0 = (q4 + 4 * i) * 8;
            *reinterpret_cast<s16x8*>(&At[r][c0]) = *reinterpret_cast<const s16x8*>(ap + c0);
        }
    }

    f32x4 acc[4][4];
    for (int mi = 0; mi < 4; ++mi)
        for (int ni = 0; ni < 4; ++ni) acc[mi][ni] = (f32x4){0.f, 0.f, 0.f, 0.f};

    for (int kt = 0; kt < 8; ++kt) {
        __syncthreads();
        {
            const short* src = wto + t * 256 + kt * 32;
            for (int ii = 0; ii < 4; ++ii)
                *reinterpret_cast<s16x8*>(&Bt[t][ii * 8]) =
                    *reinterpret_cast<const s16x8*>(src + ii * 8);
        }
        __syncthreads();
        bfrag af[4];
#pragma unroll
        for (int mi = 0; mi < 4; ++mi)
            af[mi] = *reinterpret_cast<const bfrag*>(&At[mi * 16 + lr][kt * 32 + lh * 8]);
#pragma unroll
        for (int ni = 0; ni < 4; ++ni) {
            const bfrag bf = *reinterpret_cast<const bfrag*>(&Bt[w * 64 + ni * 16 + lr][lh * 8]);
#pragma unroll
            for (int mi = 0; mi < 4; ++mi)
                acc[mi][ni] = __builtin_amdgcn_mfma_f32_16x16x32_bf16(af[mi], bf, acc[mi][ni], 0, 0, 0);
        }
    }

    for (int ni = 0; ni < 4; ++ni) {
        const int col = w * 64 + ni * 16 + lr;
        const float bb = bo[col];
        for (int mi = 0; mi < 4; ++mi) {
            const int row = m0 + mi * 16 + lh * 4;
            for (int j = 0; j < 4; ++j) {
                const int idx = (row + j) * 256 + col;
                out[idx] = acc[mi][ni][j] + bb + x[idx];
            }
        }
    }
}

// ---------------------------------------------------------------------------
extern "C" void kernel_launch(void* const* d_in, const int* in_sizes, int n_in,
                              void* d_out, int out_size, void* d_ws, size_t ws_size,
                              hipStream_t stream) {
    const float* x   = (const float*)d_in[0];
    const float* gns = (const float*)d_in[1];
    const float* gnb = (const float*)d_in[2];
    const float* Wq  = (const float*)d_in[3];
    const float* bq  = (const float*)d_in[4];
    const float* Wk  = (const float*)d_in[5];
    const float* bk  = (const float*)d_in[6];
    const float* Wv  = (const float*)d_in[7];
    const float* bv  = (const float*)d_in[8];
    const float* Wo  = (const float*)d_in[9];
    const float* bo  = (const float*)d_in[10];
    float* out = (float*)d_out;

    char* ws = (char*)d_ws;
    short* wt   = (short*)(ws);
    float* part = (float*)(ws + 524288);
    float* cA   = (float*)(ws + 589824);
    float* cB   = (float*)(ws + 622592);
    const size_t MB16 = 16777216;
    short* qb  = (short*)(ws + (1 << 20));
    short* kb  = (short*)(ws + (1 << 20) + MB16);
    short* vtb = (short*)(ws + (1 << 20) + 2 * MB16);
    short* aob = (short*)(ws + (1 << 20) + 3 * MB16);

    hipLaunchKernelGGL(prep_w,   dim3(1024), dim3(256), 0, stream, Wq, Wk, Wv, Wo, wt);
    hipLaunchKernelGGL(gn_part,  dim3(256),  dim3(256), 0, stream, x, part);
    hipLaunchKernelGGL(gn_final, dim3(32),   dim3(256), 0, stream, part, gns, gnb, cA, cB);
    hipLaunchKernelGGL(qkv_gemm, dim3(512),  dim3(256), 0, stream, x, cA, cB, wt, bq, bk, bv, qb, kb, vtb);
    hipLaunchKernelGGL(attn,     dim3(256),  dim3(512), 0, stream, qb, kb, vtb, aob);
    hipLaunchKernelGGL(oproj,    dim3(512),  dim3(256), 0, stream, aob, wt + 3 * 65536, bo, x, out);
}

// Round 5
// 151.719 us; speedup vs baseline: 1.5435x; 1.1038x over previous
//
#include <hip/hip_runtime.h>
#include <hip/hip_bf16.h>

#define EPSV  1e-5f
#define QSC   0.0625f     // C^-0.5

typedef __attribute__((ext_vector_type(8))) __bf16 bfrag;   // MFMA A/B operand
typedef __attribute__((ext_vector_type(4))) float  f32x4;
typedef __attribute__((ext_vector_type(8))) short  s16x8;
typedef __attribute__((ext_vector_type(4))) short  s16x4;

static __device__ __forceinline__ short f2b(float f) {
    __hip_bfloat16 h = __float2bfloat16(f);
    return __builtin_bit_cast(short, h);
}

// async global->LDS, 16B per lane; LDS dest = wave-uniform base + lane*16
#define GLDS16(SRC, DST) __builtin_amdgcn_global_load_lds( \
    (__attribute__((address_space(1))) void*)(SRC),        \
    (__attribute__((address_space(3))) void*)(DST), 16, 0, 0)

// ---------------------------------------------------------------------------
// K0: weights fp32 [k][n] -> bf16 transposed [n][k]  (4 matrices: q,k,v,o)
// ---------------------------------------------------------------------------
__global__ __launch_bounds__(256) void prep_w(const float* __restrict__ wq,
                                              const float* __restrict__ wk,
                                              const float* __restrict__ wv,
                                              const float* __restrict__ wo,
                                              short* __restrict__ wt) {
    const int z = blockIdx.x >> 8;
    const int n = blockIdx.x & 255;
    const int k = threadIdx.x;
    const float* w = (z == 0) ? wq : (z == 1) ? wk : (z == 2) ? wv : wo;
    wt[(z * 256 + n) * 256 + k] = f2b(w[k * 256 + n]);
}

// ---------------------------------------------------------------------------
// K1a: GroupNorm partial sums
// ---------------------------------------------------------------------------
__global__ __launch_bounds__(256) void gn_part(const float* __restrict__ x,
                                               float* __restrict__ part) {
    const int b = blockIdx.x >> 3, ch = blockIdx.x & 7;
    const int t = threadIdx.x;
    const int c4 = t & 63;
    const int rr = t >> 6;
    float s1 = 0.f, s2 = 0.f;
    for (int i = 0; i < 32; ++i) {
        const int pos = ch * 128 + rr + (i << 2);
        const f32x4 v = *reinterpret_cast<const f32x4*>(x + (((b << 10) + pos) << 8) + (c4 << 2));
        s1 += v[0] + v[1] + v[2] + v[3];
        s2 += v[0]*v[0] + v[1]*v[1] + v[2]*v[2] + v[3]*v[3];
    }
    __shared__ float ls1[256], ls2[256];
    ls1[t] = s1; ls2[t] = s2;
    __syncthreads();
    if (t < 32) {
        float a1 = 0.f, a2 = 0.f;
        for (int r2 = 0; r2 < 4; ++r2)
            for (int e = 0; e < 2; ++e) {
                const int idx = r2 * 64 + t * 2 + e;
                a1 += ls1[idx]; a2 += ls2[idx];
            }
        part[((b * 8 + ch) * 32 + t) * 2 + 0] = a1;
        part[((b * 8 + ch) * 32 + t) * 2 + 1] = a2;
    }
}

// ---------------------------------------------------------------------------
// K1b: finalize stats -> per-(b,c) affine:  ft = x*cA + cB
// ---------------------------------------------------------------------------
__global__ __launch_bounds__(256) void gn_final(const float* __restrict__ part,
                                                const float* __restrict__ gns,
                                                const float* __restrict__ gnb,
                                                float* __restrict__ cA,
                                                float* __restrict__ cB) {
    const int b = blockIdx.x, c = threadIdx.x, g = c >> 3;
    float s1 = 0.f, s2 = 0.f;
    for (int ch = 0; ch < 8; ++ch) {
        s1 += part[((b * 8 + ch) * 32 + g) * 2 + 0];
        s2 += part[((b * 8 + ch) * 32 + g) * 2 + 1];
    }
    const float mean = s1 * (1.f / 8192.f);
    const float var  = s2 * (1.f / 8192.f) - mean * mean;
    const float rstd = rsqrtf(var + EPSV);
    const float a = rstd * gns[c];
    cA[(b << 8) + c] = a;
    cB[(b << 8) + c] = gnb[c] - mean * a;
}

// ---------------------------------------------------------------------------
// K2: fused GN-normalize + QKV projection.  q pre-scaled by C^-0.5.
// B-fragments loaded DIRECTLY from global (weights L2-hot, 384 KB) into
// registers -> no B staging, no barriers in the main loop.
// v written TRANSPOSED: vt[b][c][pos]
// ---------------------------------------------------------------------------
__global__ __launch_bounds__(256) void qkv_gemm(const float* __restrict__ x,
                                                const float* __restrict__ cA,
                                                const float* __restrict__ cB,
                                                const short* __restrict__ wt,
                                                const float* __restrict__ bq,
                                                const float* __restrict__ bk,
                                                const float* __restrict__ bv,
                                                short* __restrict__ qo,
                                                short* __restrict__ ko,
                                                short* __restrict__ vtg) {
    __shared__ short At[64][264];

    const int t  = threadIdx.x;
    const int m0 = blockIdx.x * 64;
    const int b  = m0 >> 10;
    const int lane = t & 63, w = t >> 6;
    const int lr = lane & 15, lh = lane >> 4;

    // ---- A tile: load x, apply GN affine, convert to bf16 (once per block)
    {
        const int r = t >> 2, q4 = t & 3;
        const float* xrow = x + (m0 + r) * 256;
        const float* ca = cA + (b << 8);
        const float* cb = cB + (b << 8);
        for (int i = 0; i < 16; ++i) {
            const int c0 = (q4 + 4 * i) * 4;
            const f32x4 v  = *reinterpret_cast<const f32x4*>(xrow + c0);
            const f32x4 aa = *reinterpret_cast<const f32x4*>(ca + c0);
            const f32x4 bb = *reinterpret_cast<const f32x4*>(cb + c0);
            s16x4 o;
            for (int j = 0; j < 4; ++j) o[j] = f2b(v[j] * aa[j] + bb[j]);
            *reinterpret_cast<s16x4*>(&At[r][c0]) = o;
        }
    }
    __syncthreads();   // the only barrier

    for (int z = 0; z < 3; ++z) {
        f32x4 acc[4][4];
        for (int mi = 0; mi < 4; ++mi)
            for (int ni = 0; ni < 4; ++ni) acc[mi][ni] = (f32x4){0.f, 0.f, 0.f, 0.f};
        // per-lane weight base: row = w*64 + lr (+ni*16), col = lh*8 (+kt*32)
        const short* wz = wt + z * 65536 + (w * 64 + lr) * 256 + lh * 8;
#pragma unroll
        for (int kt = 0; kt < 8; ++kt) {
            bfrag bf[4];
#pragma unroll
            for (int ni = 0; ni < 4; ++ni)
                bf[ni] = *reinterpret_cast<const bfrag*>(wz + ni * 4096 + kt * 32);
            bfrag af[4];
#pragma unroll
            for (int mi = 0; mi < 4; ++mi)
                af[mi] = *reinterpret_cast<const bfrag*>(&At[mi * 16 + lr][kt * 32 + lh * 8]);
#pragma unroll
            for (int ni = 0; ni < 4; ++ni)
#pragma unroll
                for (int mi = 0; mi < 4; ++mi)
                    acc[mi][ni] = __builtin_amdgcn_mfma_f32_16x16x32_bf16(af[mi], bf[ni], acc[mi][ni], 0, 0, 0);
        }
        // epilogue
        if (z == 2) {
            for (int ni = 0; ni < 4; ++ni) {
                const int col = w * 64 + ni * 16 + lr;
                const float bb = bv[col];
                for (int mi = 0; mi < 4; ++mi) {
                    const int pos = (m0 & 1023) + mi * 16 + lh * 4;
                    s16x4 ov;
                    for (int j = 0; j < 4; ++j) ov[j] = f2b(acc[mi][ni][j] + bb);
                    *reinterpret_cast<s16x4*>(&vtg[(((b << 8) + col) << 10) + pos]) = ov;
                }
            }
        } else {
            short* outp = (z == 0) ? qo : ko;
            const float* bias = (z == 0) ? bq : bk;
            const float s = (z == 0) ? QSC : 1.0f;
            for (int ni = 0; ni < 4; ++ni) {
                const int col = w * 64 + ni * 16 + lr;
                const float bsc = bias[col] * s;
                for (int mi = 0; mi < 4; ++mi) {
                    const int row = m0 + mi * 16 + lh * 4;
                    for (int j = 0; j < 4; ++j)
                        outp[(row + j) * 256 + col] = f2b(acc[mi][ni][j] * s + bsc);
                }
            }
        }
    }
}

// ---------------------------------------------------------------------------
// K3: flash attention, 8 waves (512 thr), QBLK=128 per block.
// grid = 256 (XCD-swizzled) = 1 block/CU, 2 waves/SIMD.
// Double-buffered K/V via global_load_lds, raw s_barrier + counted vmcnt(8).
// Swapped QK^T (mfma(K,Q)); per-lane softmax; wave-uniform skip-rescale.
// ---------------------------------------------------------------------------
__global__ __launch_bounds__(512) void attn(const short* __restrict__ qq,
                                            const short* __restrict__ kk,
                                            const short* __restrict__ vt,
                                            short* __restrict__ ao) {
    __shared__ __align__(1024) short Kt[2][64 * 256];   // 2 x 32 KB
    __shared__ __align__(1024) short Vt[2][256 * 64];   // 2 x 32 KB
    __shared__ __align__(1024) short Pl[8][16 * 64];    // 16 KB (per-wave)

    int bid = blockIdx.x;
    bid = ((bid & 7) << 5) | (bid >> 3);   // XCD swizzle: 4 batches/XCD in L2
    const int b = bid >> 3, qt = bid & 7;
    const int t = threadIdx.x;
    const int w = t >> 6, lane = t & 63;
    const int lr = lane & 15, lh = lane >> 4;
    const int qr0 = qt * 128 + w * 16;
    const int sw = lr & 7;

    bfrag qf[8];
    {
        const short* qp = qq + (((b << 10) + qr0 + lr) << 8) + lh * 8;
#pragma unroll
        for (int ks = 0; ks < 8; ++ks)
            qf[ks] = *reinterpret_cast<const bfrag*>(qp + ks * 32);
    }

    const short* kbase = kk + ((long)b << 18);
    const short* vbase = vt + ((long)b << 18);
    short* plw = Pl[w];

    auto stageK = [&](int kt_, int buf) {
#pragma unroll
        for (int t2 = 0; t2 < 4; ++t2) {
            const int rbase = w * 8 + t2 * 2;
            const int r  = rbase + (lane >> 5);
            const int gs = (lane & 31) ^ (r & 7);
            GLDS16(kbase + ((kt_ * 64 + r) << 8) + (gs << 3), &Kt[buf][rbase << 8]);
        }
    };
    auto stageV = [&](int kt_, int buf) {
#pragma unroll
        for (int t2 = 0; t2 < 4; ++t2) {
            const int rbase = w * 32 + t2 * 8;
            const int r  = rbase + (lane >> 3);
            const int gs = (lane & 7) ^ (r & 7);
            GLDS16(vbase + (r << 10) + kt_ * 64 + (gs << 3), &Vt[buf][rbase << 6]);
        }
    };

    f32x4 o[16];
#pragma unroll
    for (int ci = 0; ci < 16; ++ci) o[ci] = (f32x4){0.f, 0.f, 0.f, 0.f};
    float m = -3e38f, lsum = 0.f;

    stageK(0, 0); stageV(0, 0);

    for (int kt = 0; kt < 16; ++kt) {
        const int cur = kt & 1;
        __asm__ volatile("s_barrier" ::: "memory");
        if (kt < 15) {
            stageK(kt + 1, cur ^ 1);
            stageV(kt + 1, cur ^ 1);
            __asm__ volatile("s_waitcnt vmcnt(8)" ::: "memory");
        } else {
            __asm__ volatile("s_waitcnt vmcnt(0)" ::: "memory");
        }
        __asm__ volatile("s_barrier" ::: "memory");

        // ---- S^T = K . Q
        f32x4 sacc[4];
#pragma unroll
        for (int ni = 0; ni < 4; ++ni) sacc[ni] = (f32x4){0.f, 0.f, 0.f, 0.f};
        __builtin_amdgcn_s_setprio(1);
#pragma unroll
        for (int ks = 0; ks < 8; ++ks) {
#pragma unroll
            for (int ni = 0; ni < 4; ++ni) {
                const int row = ni * 16 + lr;
                const bfrag kf = *reinterpret_cast<const bfrag*>(
                    &Kt[cur][(row << 8) + ((((ks << 2) + lh) ^ sw) << 3)]);
                sacc[ni] = __builtin_amdgcn_mfma_f32_16x16x32_bf16(kf, qf[ks], sacc[ni], 0, 0, 0);
            }
        }
        __builtin_amdgcn_s_setprio(0);

        // ---- online softmax, per-lane state for q-row lr
        float rm = fmaxf(fmaxf(sacc[0][0], sacc[0][1]), fmaxf(sacc[0][2], sacc[0][3]));
#pragma unroll
        for (int ni = 1; ni < 4; ++ni)
            rm = fmaxf(rm, fmaxf(fmaxf(sacc[ni][0], sacc[ni][1]),
                                 fmaxf(sacc[ni][2], sacc[ni][3])));
        rm = fmaxf(rm, __shfl_xor(rm, 16));
        rm = fmaxf(rm, __shfl_xor(rm, 32));

        const bool grow = __any(rm > m);
        float p[4][4];
        float rs = 0.f;
        if (grow) {
            const float mn = fmaxf(m, rm);
            const float sc = __expf(m - mn);
            m = mn;
#pragma unroll
            for (int ni = 0; ni < 4; ++ni)
#pragma unroll
                for (int r2 = 0; r2 < 4; ++r2) {
                    p[ni][r2] = __expf(sacc[ni][r2] - mn);
                    rs += p[ni][r2];
                }
            rs += __shfl_xor(rs, 16);
            rs += __shfl_xor(rs, 32);
            lsum = lsum * sc + rs;
            float scb[4];
#pragma unroll
            for (int j = 0; j < 4; ++j) scb[j] = __shfl(sc, lh * 4 + j);
#pragma unroll
            for (int ci = 0; ci < 16; ++ci)
#pragma unroll
                for (int j = 0; j < 4; ++j) o[ci][j] *= scb[j];
        } else {
#pragma unroll
            for (int ni = 0; ni < 4; ++ni)
#pragma unroll
                for (int r2 = 0; r2 < 4; ++r2) {
                    p[ni][r2] = __expf(sacc[ni][r2] - m);
                    rs += p[ni][r2];
                }
            rs += __shfl_xor(rs, 16);
            rs += __shfl_xor(rs, 32);
            lsum += rs;
        }

        // ---- stage P
#pragma unroll
        for (int ni = 0; ni < 4; ++ni) {
            s16x4 pw;
#pragma unroll
            for (int r2 = 0; r2 < 4; ++r2) pw[r2] = f2b(p[ni][r2]);
            const int gc = (ni << 1) + (lh >> 1);
            const int ad = (lr << 6) + ((gc ^ sw) << 3) + ((lh & 1) << 2);
            *reinterpret_cast<s16x4*>(&plw[ad]) = pw;
        }
        const bfrag pa0 = *reinterpret_cast<const bfrag*>(
            &plw[(lr << 6) + ((lh ^ sw) << 3)]);
        const bfrag pa1 = *reinterpret_cast<const bfrag*>(
            &plw[(lr << 6) + (((4 + lh) ^ sw) << 3)]);

        // ---- O += P . V
        __builtin_amdgcn_s_setprio(1);
#pragma unroll
        for (int ci = 0; ci < 16; ++ci) {
            const int row = (ci << 4) + lr;
            const bfrag vb0 = *reinterpret_cast<const bfrag*>(
                &Vt[cur][(row << 6) + ((lh ^ sw) << 3)]);
            const bfrag vb1 = *reinterpret_cast<const bfrag*>(
                &Vt[cur][(row << 6) + (((4 + lh) ^ sw) << 3)]);
            o[ci] = __builtin_amdgcn_mfma_f32_16x16x32_bf16(pa0, vb0, o[ci], 0, 0, 0);
            o[ci] = __builtin_amdgcn_mfma_f32_16x16x32_bf16(pa1, vb1, o[ci], 0, 0, 0);
        }
        __builtin_amdgcn_s_setprio(0);
    }

    float invb[4];
#pragma unroll
    for (int j = 0; j < 4; ++j) invb[j] = 1.0f / __shfl(lsum, lh * 4 + j);
#pragma unroll
    for (int j = 0; j < 4; ++j) {
        const int row = (b << 10) + qr0 + lh * 4 + j;
        for (int ci = 0; ci < 16; ++ci)
            ao[(row << 8) + (ci << 4) + lr] = f2b(o[ci][j] * invb[j]);
    }
}

// ---------------------------------------------------------------------------
// K4: output projection + bias + residual.  B direct from global (L2-hot),
// no barriers after the A-tile stage.
// ---------------------------------------------------------------------------
__global__ __launch_bounds__(256) void oproj(const short* __restrict__ ao,
                                             const short* __restrict__ wto,
                                             const float* __restrict__ bo,
                                             const float* __restrict__ x,
                                             float* __restrict__ out) {
    __shared__ short At[64][264];

    const int t  = threadIdx.x;
    const int m0 = blockIdx.x * 64;
    const int lane = t & 63, w = t >> 6;
    const int lr = lane & 15, lh = lane >> 4;

    {
        const int r = t >> 2, q4 = t & 3;
        const short* ap = ao + (m0 + r) * 256;
        for (int i = 0; i < 8; ++i) {
            const int c0 = (q4 + 4 * i) * 8;
            *reinterpret_cast<s16x8*>(&At[r][c0]) = *reinterpret_cast<const s16x8*>(ap + c0);
        }
    }
    __syncthreads();   // the only barrier

    f32x4 acc[4][4];
    for (int mi = 0; mi < 4; ++mi)
        for (int ni = 0; ni < 4; ++ni) acc[mi][ni] = (f32x4){0.f, 0.f, 0.f, 0.f};

    const short* wz = wto + (w * 64 + lr) * 256 + lh * 8;
#pragma unroll
    for (int kt = 0; kt < 8; ++kt) {
        bfrag bf[4];
#pragma unroll
        for (int ni = 0; ni < 4; ++ni)
            bf[ni] = *reinterpret_cast<const bfrag*>(wz + ni * 4096 + kt * 32);
        bfrag af[4];
#pragma unroll
        for (int mi = 0; mi < 4; ++mi)
            af[mi] = *reinterpret_cast<const bfrag*>(&At[mi * 16 + lr][kt * 32 + lh * 8]);
#pragma unroll
        for (int ni = 0; ni < 4; ++ni)
#pragma unroll
            for (int mi = 0; mi < 4; ++mi)
                acc[mi][ni] = __builtin_amdgcn_mfma_f32_16x16x32_bf16(af[mi], bf[ni], acc[mi][ni], 0, 0, 0);
    }

    for (int ni = 0; ni < 4; ++ni) {
        const int col = w * 64 + ni * 16 + lr;
        const float bb = bo[col];
        for (int mi = 0; mi < 4; ++mi) {
            const int row = m0 + mi * 16 + lh * 4;
            for (int j = 0; j < 4; ++j) {
                const int idx = (row + j) * 256 + col;
                out[idx] = acc[mi][ni][j] + bb + x[idx];
            }
        }
    }
}

// ---------------------------------------------------------------------------
extern "C" void kernel_launch(void* const* d_in, const int* in_sizes, int n_in,
                              void* d_out, int out_size, void* d_ws, size_t ws_size,
                              hipStream_t stream) {
    const float* x   = (const float*)d_in[0];
    const float* gns = (const float*)d_in[1];
    const float* gnb = (const float*)d_in[2];
    const float* Wq  = (const float*)d_in[3];
    const float* bq  = (const float*)d_in[4];
    const float* Wk  = (const float*)d_in[5];
    const float* bk  = (const float*)d_in[6];
    const float* Wv  = (const float*)d_in[7];
    const float* bv  = (const float*)d_in[8];
    const float* Wo  = (const float*)d_in[9];
    const float* bo  = (const float*)d_in[10];
    float* out = (float*)d_out;

    char* ws = (char*)d_ws;
    short* wt   = (short*)(ws);
    float* part = (float*)(ws + 524288);
    float* cA   = (float*)(ws + 589824);
    float* cB   = (float*)(ws + 622592);
    const size_t MB16 = 16777216;
    short* qb  = (short*)(ws + (1 << 20));
    short* kb  = (short*)(ws + (1 << 20) + MB16);
    short* vtb = (short*)(ws + (1 << 20) + 2 * MB16);
    short* aob = (short*)(ws + (1 << 20) + 3 * MB16);

    hipLaunchKernelGGL(prep_w,   dim3(1024), dim3(256), 0, stream, Wq, Wk, Wv, Wo, wt);
    hipLaunchKernelGGL(gn_part,  dim3(256),  dim3(256), 0, stream, x, part);
    hipLaunchKernelGGL(gn_final, dim3(32),   dim3(256), 0, stream, part, gns, gnb, cA, cB);
    hipLaunchKernelGGL(qkv_gemm, dim3(512),  dim3(256), 0, stream, x, cA, cB, wt, bq, bk, bv, qb, kb, vtb);
    hipLaunchKernelGGL(attn,     dim3(256),  dim3(512), 0, stream, qb, kb, vtb, aob);
    hipLaunchKernelGGL(oproj,    dim3(512),  dim3(256), 0, stream, aob, wt + 3 * 65536, bo, x, out);
}